// Round 7
// baseline (558.299 us; speedup 1.0000x reference)
//
#include <hip/hip_runtime.h>
#include <hip/hip_bf16.h>
#include <math.h>

#define T_TOK 8192
#define NE 1024
#define N_EXP 8
#define DFFN 2048
#define TW 16384        // total width = 8*2048
#define P_TOT 16384     // T_TOK * 2

#define TILE_M 256
#define TILE_N 256
#define BKT 64

typedef __attribute__((ext_vector_type(8))) short bf16x8;
typedef __attribute__((ext_vector_type(4))) float f32x4;

#define GLOAD_LDS16(g, l) __builtin_amdgcn_global_load_lds( \
    (const __attribute__((address_space(1))) void*)(g), \
    (__attribute__((address_space(3))) void*)(l), 16, 0, 0)

static __device__ __forceinline__ unsigned short f2bf(float f) {
    __hip_bfloat16 b = __float2bfloat16(f);
    return *(unsigned short*)&b;
}

// ---------------------------------------------------------------------------
// Kernel A: router — logits, softmax, top-2, normalized weights, loss partials
// ---------------------------------------------------------------------------
__global__ __launch_bounds__(256) void router_kernel(
    const float* __restrict__ x, const float* __restrict__ wr,
    int* __restrict__ sel_idx, float* __restrict__ sel_wt,
    float* __restrict__ z_part, float* __restrict__ p_part)
{
    __shared__ float wrs[N_EXP * NE];   // 32 KB
    __shared__ float red[256];
    int tid = threadIdx.x;
    for (int i = tid; i < N_EXP * NE; i += 256) wrs[i] = wr[i];
    __syncthreads();

    int t = blockIdx.x * 256 + tid;   // T_TOK == 32*256 exactly
    float lg[N_EXP];
#pragma unroll
    for (int e = 0; e < N_EXP; e++) lg[e] = 0.f;

    const float4* x4 = (const float4*)(x + (size_t)t * NE);
    for (int n4 = 0; n4 < NE / 4; n4++) {
        float4 xv = x4[n4];
#pragma unroll
        for (int e = 0; e < N_EXP; e++) {
            const float* w = &wrs[e * NE + n4 * 4];
            lg[e] += xv.x * w[0] + xv.y * w[1] + xv.z * w[2] + xv.w * w[3];
        }
    }

    float m = lg[0];
#pragma unroll
    for (int e = 1; e < N_EXP; e++) m = fmaxf(m, lg[e]);
    float p[N_EXP], s = 0.f;
#pragma unroll
    for (int e = 0; e < N_EXP; e++) { p[e] = expf(lg[e] - m); s += p[e]; }
    float inv = 1.f / s;
#pragma unroll
    for (int e = 0; e < N_EXP; e++) p[e] *= inv;
    float lse = m + logf(s);

    int e0 = 0;
#pragma unroll
    for (int e = 1; e < N_EXP; e++) if (p[e] > p[e0]) e0 = e;
    int e1 = (e0 == 0) ? 1 : 0;
#pragma unroll
    for (int e = 0; e < N_EXP; e++) if (e != e0 && p[e] > p[e1]) e1 = e;

    float wn = 1.f / (p[e0] + p[e1]);
    sel_idx[t * 2 + 0] = e0;
    sel_idx[t * 2 + 1] = e1;
    sel_wt[t * 2 + 0] = p[e0] * wn;
    sel_wt[t * 2 + 1] = p[e1] * wn;

    red[tid] = lse * lse;
    __syncthreads();
    for (int st = 128; st > 0; st >>= 1) {
        if (tid < st) red[tid] += red[tid + st];
        __syncthreads();
    }
    if (tid == 0) z_part[blockIdx.x] = red[0];
#pragma unroll
    for (int e = 0; e < N_EXP; e++) {
        __syncthreads();
        red[tid] = p[e];
        __syncthreads();
        for (int st = 128; st > 0; st >>= 1) {
            if (tid < st) red[tid] += red[tid + st];
            __syncthreads();
        }
        if (tid == 0) p_part[blockIdx.x * N_EXP + e] = red[0];
    }
}

// ---------------------------------------------------------------------------
// Kernel B: counts (by scan), offsets, cursors, tile table, aux-loss outputs
// ---------------------------------------------------------------------------
__global__ __launch_bounds__(256) void finalize_router(
    const int* __restrict__ sel_idx,
    const float* __restrict__ z_part, const float* __restrict__ p_part,
    int* __restrict__ cnt, int* __restrict__ off, int* __restrict__ cursor,
    int* __restrict__ tile_tab, int* __restrict__ tile_n,
    float* __restrict__ out)
{
    __shared__ int redc[256];
    __shared__ int cnts[N_EXP];
    int tid = threadIdx.x;
    int c[N_EXP];
#pragma unroll
    for (int e = 0; e < N_EXP; e++) c[e] = 0;
    for (int i = tid; i < P_TOT; i += 256) c[sel_idx[i]]++;
#pragma unroll
    for (int e = 0; e < N_EXP; e++) {
        redc[tid] = c[e];
        __syncthreads();
        for (int st = 128; st > 0; st >>= 1) {
            if (tid < st) redc[tid] += redc[tid + st];
            __syncthreads();
        }
        if (tid == 0) cnts[e] = redc[0];
        __syncthreads();
    }
    if (tid == 0) {
        int o = 0;
        int nt = 0;
        for (int e = 0; e < N_EXP; e++) {
            cnt[e] = cnts[e];
            off[e] = o;
            o += cnts[e];
            cursor[e] = 0;
            for (int rb = 0; rb < cnts[e]; rb += TILE_M)
                tile_tab[nt++] = (e << 20) | rb;
        }
        off[N_EXP] = o;
        tile_n[0] = nt;
        float zs = 0.f;
        for (int b = 0; b < 32; b++) zs += z_part[b];
        float lb = 0.f;
        float* tail = out + (size_t)T_TOK * NE;
        for (int e = 0; e < N_EXP; e++) {
            float ps = 0.f;
            for (int b = 0; b < 32; b++) ps += p_part[b * N_EXP + e];
            float fi = (float)cnts[e] / (float)P_TOT;
            float pi = ps / (float)T_TOK;
            lb += fi * pi;
            tail[2 + e] = fi;
        }
        tail[0] = zs / (float)T_TOK;       // router_z_loss
        tail[1] = 8.f * lb;                // load_balance_loss
    }
}

// ---------------------------------------------------------------------------
// Kernel C: scatter (token,slot) pairs into per-expert lists
// ---------------------------------------------------------------------------
__global__ __launch_bounds__(256) void scatter_kernel(
    const int* __restrict__ sel_idx, const int* __restrict__ off,
    int* __restrict__ cursor, int* __restrict__ token_list)
{
    int i = blockIdx.x * 256 + threadIdx.x;
    if (i < P_TOT) {
        int e = sel_idx[i];
        int pos = atomicAdd(&cursor[e], 1);
        token_list[off[e] + pos] = i;   // token = i>>1, slot = i&1
    }
}

// ---------------------------------------------------------------------------
// Kernel G: gather + convert: xg[p,:] = bf16(x[tok(p),:]) (expert-sorted A)
// ---------------------------------------------------------------------------
__global__ __launch_bounds__(256) void gather_x_kernel(
    const float* __restrict__ x, const int* __restrict__ token_list,
    unsigned short* __restrict__ xg)
{
    int idx = blockIdx.x * 256 + threadIdx.x;
    int p = idx >> 7, c8 = (idx & 127) << 3;
    int tok = token_list[p] >> 1;
    const float4* s = (const float4*)(x + (size_t)tok * NE + c8);
    float4 v0 = s[0], v1 = s[1];
    ushort4 o0, o1;
    o0.x = f2bf(v0.x); o0.y = f2bf(v0.y); o0.z = f2bf(v0.z); o0.w = f2bf(v0.w);
    o1.x = f2bf(v1.x); o1.y = f2bf(v1.y); o1.z = f2bf(v1.z); o1.w = f2bf(v1.w);
    *(ushort4*)&xg[(size_t)p * NE + c8] = o0;
    *(ushort4*)&xg[(size_t)p * NE + c8 + 4] = o1;
}

// ---------------------------------------------------------------------------
// Kernel P2: transpose + convert: src [R][C] f32 -> dst [C][R] bf16
// ---------------------------------------------------------------------------
__global__ __launch_bounds__(256) void transpose_bf16_kernel(
    const float* __restrict__ src, unsigned short* __restrict__ dst,
    int R, int C)
{
    __shared__ float tile[64][65];
    int rb = blockIdx.y * 64, cb = blockIdx.x * 64;
    int tid = threadIdx.x;
#pragma unroll
    for (int p = 0; p < 4; p++) {
        int idx = p * 256 + tid;
        int r = idx >> 4, c4 = (idx & 15) << 2;
        float4 v = *(const float4*)&src[(size_t)(rb + r) * C + cb + c4];
        tile[r][c4 + 0] = v.x; tile[r][c4 + 1] = v.y;
        tile[r][c4 + 2] = v.z; tile[r][c4 + 3] = v.w;
    }
    __syncthreads();
#pragma unroll
    for (int p = 0; p < 4; p++) {
        int idx = p * 256 + tid;
        int c = idx >> 4, r4 = (idx & 15) << 2;
        ushort4 o;
        o.x = f2bf(tile[r4 + 0][c]); o.y = f2bf(tile[r4 + 1][c]);
        o.z = f2bf(tile[r4 + 2][c]); o.w = f2bf(tile[r4 + 3][c]);
        *(ushort4*)&dst[(size_t)(cb + c) * R + rb + r4] = o;
    }
}

// ---------------------------------------------------------------------------
// 8-phase grouped GEMM core. 256x256 tile, BK=64, 8 waves (2M x 4N), per-wave
// 128x64 (acc[8][4]). 128 KB dynamic LDS (dbuf A + dbuf B). Per K-tile, 4
// phases {ds_read quadrant; issue 2 gload_lds; [vmcnt(2) @ p0,p3]; s_barrier;
// lgkmcnt(0); setprio(1); 16 MFMA; setprio(0); s_barrier}. vmcnt never 0 in
// the main loop. XOR chunk swizzle (verified 0-conflict): source chunk
// ksw=(lane&7)^((lane>>3)&7); read slot (kk*4+kq)^(rr&7). B LDS rows are
// col-permuted pi(l) = ((l>>5)&3)*64 + (l>>7)*32 + (l&31) so the nh phase
// axis aligns with 64-row staging granules.
// ---------------------------------------------------------------------------
#define ISSA(buf, i, kofs) GLOAD_LDS16(ga[i] + (kofs), Asm + (buf)*16384 + ((i)*4096 + wid*512))
#define ISSB(buf, i, kofs) GLOAD_LDS16(gb[i] + (kofs), Bsm + (buf)*16384 + ((i)*4096 + wid*512))

#define LDA_(m, ks)      (*(const bf16x8*)&Ac[arow[m] + (ks)])
#define LDB_(nh, j, ks)  (*(const bf16x8*)&Bc[brow[(nh)*2+(j)] + (ks)])

#define PHASE_TAIL(NMFMA_BLOCK)                                   \
    __builtin_amdgcn_s_barrier();                                 \
    asm volatile("s_waitcnt lgkmcnt(0)" ::: "memory");            \
    __builtin_amdgcn_sched_barrier(0);                            \
    __builtin_amdgcn_s_setprio(1);                                \
    NMFMA_BLOCK                                                   \
    __builtin_amdgcn_s_setprio(0);                                \
    __builtin_amdgcn_sched_barrier(0);                            \
    __builtin_amdgcn_s_barrier();

#define MFMA16(n0, n1, AF, B0, B1)                                \
    _Pragma("unroll")                                             \
    for (int m = 0; m < 8; m++) {                                 \
        acc[m][n0] = __builtin_amdgcn_mfma_f32_16x16x32_bf16(AF[m], B0, acc[m][n0], 0, 0, 0); \
        acc[m][n1] = __builtin_amdgcn_mfma_f32_16x16x32_bf16(AF[m], B1, acc[m][n1], 0, 0, 0); \
    }

#define GEMM8_LOOP(NKT)                                                     \
    /* prologue: full tile 0 */                                             \
    _Pragma("unroll")                                                       \
    for (int i = 0; i < 4; i++) { ISSA(0, i, 0); ISSB(0, i, 0); }           \
    asm volatile("s_waitcnt vmcnt(0)" ::: "memory");                        \
    __builtin_amdgcn_s_barrier();                                           \
    for (int t = 0; t < (NKT); t++) {                                       \
        const int cur = t & 1, nxt = cur ^ 1;                               \
        const bool pf = (t + 1 < (NKT));                                    \
        const int kofs = (t + 1) * BKT;                                     \
        const __hip_bfloat16* Ac = Asm + cur * 16384;                       \
        const __hip_bfloat16* Bc = Bsm + cur * 16384;                       \
        bf16x8 af[8], b0, b1;                                               \
        /* phase 0: kk=0, nh=0 */                                           \
        _Pragma("unroll")                                                   \
        for (int m = 0; m < 8; m++) af[m] = LDA_(m, ks0);                   \
        b0 = LDB_(0, 0, ks0); b1 = LDB_(0, 1, ks0);                         \
        if (pf) { ISSA(nxt, 0, kofs); ISSA(nxt, 1, kofs);                   \
                  asm volatile("s_waitcnt vmcnt(2)" ::: "memory"); }        \
        else    { asm volatile("s_waitcnt vmcnt(0)" ::: "memory"); }        \
        PHASE_TAIL(MFMA16(0, 1, af, b0, b1))                                \
        /* phase 1: kk=0, nh=1 */                                           \
        b0 = LDB_(1, 0, ks0); b1 = LDB_(1, 1, ks0);                         \
        if (pf) { ISSA(nxt, 2, kofs); ISSA(nxt, 3, kofs); }                 \
        PHASE_TAIL(MFMA16(2, 3, af, b0, b1))                                \
        /* phase 2: kk=1, nh=0 */                                           \
        _Pragma("unroll")                                                   \
        for (int m = 0; m < 8; m++) af[m] = LDA_(m, ks1);                   \
        b0 = LDB_(0, 0, ks1); b1 = LDB_(0, 1, ks1);                         \
        if (pf) { ISSB(nxt, 0, kofs); ISSB(nxt, 1, kofs); }                 \
        PHASE_TAIL(MFMA16(0, 1, af, b0, b1))                                \
        /* phase 3: kk=1, nh=1 */                                           \
        b0 = LDB_(1, 0, ks1); b1 = LDB_(1, 1, ks1);                         \
        if (pf) { ISSB(nxt, 2, kofs); ISSB(nxt, 3, kofs);                   \
                  asm volatile("s_waitcnt vmcnt(2)" ::: "memory"); }        \
        else    { asm volatile("s_waitcnt vmcnt(0)" ::: "memory"); }        \
        PHASE_TAIL(MFMA16(2, 3, af, b0, b1))                                \
    }

// ---------------------------------------------------------------------------
// Kernel D: grouped GEMM1:  h[p,:] = selw[p] * gelu(xg[p,:] @ W1_e)
// ---------------------------------------------------------------------------
__global__ __launch_bounds__(512, 1) void gemm1_mfma(
    const __hip_bfloat16* __restrict__ xg, const __hip_bfloat16* __restrict__ w1t,
    const int* __restrict__ token_list, const float* __restrict__ sel_wt,
    const int* __restrict__ cnt, const int* __restrict__ off,
    const int* __restrict__ tile_tab, const int* __restrict__ tile_n,
    __hip_bfloat16* __restrict__ h)
{
    extern __shared__ __align__(16) __hip_bfloat16 smem[];
    __hip_bfloat16* Asm = smem;            // 2 x 16384 elems
    __hip_bfloat16* Bsm = smem + 32768;    // 2 x 16384 elems

    int flat = blockIdx.x;
    if (flat >= tile_n[0]) return;
    int tab = tile_tab[flat];
    int e = tab >> 20, rowbase = tab & 0xFFFFF;
    int off_e = off[e];
    int rows_e = cnt[e] - rowbase;
    int colbase = blockIdx.y * TILE_N;

    int tid = threadIdx.x;
    int wid = tid >> 6, lane = tid & 63;
    int wm = wid >> 2, wn = wid & 3;
    int rr = lane & 15, kq = lane >> 4;
    int rs = rr & 7;
    int ks0 = ((0 * 4 + kq) ^ rs) * 8;
    int ks1 = ((1 * 4 + kq) ^ rs) * 8;
    int ksw = (lane & 7) ^ ((lane >> 3) & 7);

    int arow[8], brow[4];
#pragma unroll
    for (int m = 0; m < 8; m++) arow[m] = (wm * 128 + m * 16 + rr) * 64;
#pragma unroll
    for (int n = 0; n < 4; n++) brow[n] = ((n >> 1) * 128 + wn * 32 + (n & 1) * 16 + rr) * 64;

    const __hip_bfloat16* ga[4];
    const __hip_bfloat16* gb[4];
#pragma unroll
    for (int i = 0; i < 4; i++) {
        int r = i * 64 + wid * 8 + (lane >> 3);
        int ar = (r < rows_e) ? r : 0;
        ga[i] = xg + ((size_t)off_e + rowbase + ar) * NE + ksw * 8;
        int l = r;                                   // B LDS row index
        int c = ((l >> 5) & 3) * 64 + (l >> 7) * 32 + (l & 31);   // pi(l)
        gb[i] = w1t + (size_t)(e * DFFN + colbase + c) * NE + ksw * 8;
    }

    f32x4 acc[8][4] = {};
    GEMM8_LOOP(NE / BKT)

    int colg = colbase + wn * 64;
#pragma unroll
    for (int m = 0; m < 8; m++) {
#pragma unroll
        for (int j = 0; j < 4; j++) {
            int r = wm * 128 + m * 16 + kq * 4 + j;
            if (r < rows_e) {
                size_t p = (size_t)off_e + rowbase + r;
                float wgt = sel_wt[token_list[p]];
#pragma unroll
                for (int n = 0; n < 4; n++) {
                    float v = acc[m][n][j];
                    float g = 0.5f * v * (1.f + erff(v * 0.70710678118f));
                    h[p * DFFN + colg + n * 16 + rr] = __float2bfloat16(wgt * g);
                }
            }
        }
    }
}

// ---------------------------------------------------------------------------
// Kernel E: grouped GEMM2:  out[tok(p),:] += h[p,:] @ W2_e  (split-K=2, atomic)
// ---------------------------------------------------------------------------
__global__ __launch_bounds__(512, 1) void gemm2_mfma(
    const __hip_bfloat16* __restrict__ h, const __hip_bfloat16* __restrict__ w2t,
    const int* __restrict__ token_list,
    const int* __restrict__ cnt, const int* __restrict__ off,
    const int* __restrict__ tile_tab, const int* __restrict__ tile_n,
    float* __restrict__ out)
{
    extern __shared__ __align__(16) __hip_bfloat16 smem[];
    __hip_bfloat16* Asm = smem;
    __hip_bfloat16* Bsm = smem + 32768;

    int flat = blockIdx.x;
    if (flat >= tile_n[0]) return;
    int tab = tile_tab[flat];
    int e = tab >> 20, rowbase = tab & 0xFFFFF;
    int off_e = off[e];
    int rows_e = cnt[e] - rowbase;
    int colbase = blockIdx.y * TILE_N;
    int k0 = blockIdx.z * (DFFN / 2);

    int tid = threadIdx.x;
    int wid = tid >> 6, lane = tid & 63;
    int wm = wid >> 2, wn = wid & 3;
    int rr = lane & 15, kq = lane >> 4;
    int rs = rr & 7;
    int ks0 = ((0 * 4 + kq) ^ rs) * 8;
    int ks1 = ((1 * 4 + kq) ^ rs) * 8;
    int ksw = (lane & 7) ^ ((lane >> 3) & 7);

    int arow[8], brow[4];
#pragma unroll
    for (int m = 0; m < 8; m++) arow[m] = (wm * 128 + m * 16 + rr) * 64;
#pragma unroll
    for (int n = 0; n < 4; n++) brow[n] = ((n >> 1) * 128 + wn * 32 + (n & 1) * 16 + rr) * 64;

    const __hip_bfloat16* ga[4];
    const __hip_bfloat16* gb[4];
#pragma unroll
    for (int i = 0; i < 4; i++) {
        int r = i * 64 + wid * 8 + (lane >> 3);
        int ar = (r < rows_e) ? r : 0;
        ga[i] = h + ((size_t)off_e + rowbase + ar) * DFFN + k0 + ksw * 8;
        int l = r;
        int c = ((l >> 5) & 3) * 64 + (l >> 7) * 32 + (l & 31);
        gb[i] = w2t + (size_t)(colbase + c) * TW + e * DFFN + k0 + ksw * 8;
    }

    f32x4 acc[8][4] = {};
    GEMM8_LOOP((DFFN / 2) / BKT)

    int colg = colbase + wn * 64;
#pragma unroll
    for (int m = 0; m < 8; m++) {
#pragma unroll
        for (int j = 0; j < 4; j++) {
            int r = wm * 128 + m * 16 + kq * 4 + j;
            if (r < rows_e) {
                size_t p = (size_t)off_e + rowbase + r;
                int tok = token_list[p] >> 1;
#pragma unroll
                for (int n = 0; n < 4; n++)
                    atomicAdd(&out[(size_t)tok * NE + colg + n * 16 + rr],
                              acc[m][n][j]);
            }
        }
    }
}

// ---------------------------------------------------------------------------
extern "C" void kernel_launch(void* const* d_in, const int* in_sizes, int n_in,
                              void* d_out, int out_size, void* d_ws, size_t ws_size,
                              hipStream_t stream)
{
    const float* x  = (const float*)d_in[0];
    const float* wr = (const float*)d_in[1];
    const float* w1 = (const float*)d_in[2];
    const float* w2 = (const float*)d_in[3];
    float* out = (float*)d_out;

    // workspace layout (~168 MB)
    char* ws = (char*)d_ws;
    size_t o = 0;
    __hip_bfloat16* h   = (__hip_bfloat16*)(ws + o); o += (size_t)P_TOT * DFFN * 2;  // 67.1MB
    __hip_bfloat16* xg  = (__hip_bfloat16*)(ws + o); o += (size_t)P_TOT * NE * 2;    // 33.6MB
    __hip_bfloat16* w1t = (__hip_bfloat16*)(ws + o); o += (size_t)NE * TW * 2;       // 33.6MB  [TW][NE]
    __hip_bfloat16* w2t = (__hip_bfloat16*)(ws + o); o += (size_t)TW * NE * 2;       // 33.6MB  [NE][TW]
    int*   sel_idx    = (int*)(ws + o);   o += P_TOT * 4;
    float* sel_wt     = (float*)(ws + o); o += P_TOT * 4;
    int*   token_list = (int*)(ws + o);   o += P_TOT * 4;
    int*   cnt        = (int*)(ws + o);   o += 64;
    int*   off        = (int*)(ws + o);   o += 64;
    int*   cursor     = (int*)(ws + o);   o += 64;
    int*   tile_tab   = (int*)(ws + o);   o += 256 * 4;
    int*   tile_n     = (int*)(ws + o);   o += 64;
    float* z_part     = (float*)(ws + o); o += 32 * 4;
    float* p_part     = (float*)(ws + o); o += 32 * N_EXP * 4;

    // allow 128 KB dynamic LDS (cheap, idempotent; not a stream op)
    hipFuncSetAttribute((const void*)gemm1_mfma,
                        hipFuncAttributeMaxDynamicSharedMemorySize, 131072);
    hipFuncSetAttribute((const void*)gemm2_mfma,
                        hipFuncAttributeMaxDynamicSharedMemorySize, 131072);

    hipMemsetAsync(d_out, 0, (size_t)out_size * sizeof(float), stream);

    router_kernel<<<32, 256, 0, stream>>>(x, wr, sel_idx, sel_wt, z_part, p_part);
    finalize_router<<<1, 256, 0, stream>>>(sel_idx, z_part, p_part, cnt, off, cursor,
                                           tile_tab, tile_n, out);
    scatter_kernel<<<64, 256, 0, stream>>>(sel_idx, off, cursor, token_list);
    gather_x_kernel<<<P_TOT * (NE / 8) / 256, 256, 0, stream>>>(x, token_list,
                                                                (unsigned short*)xg);
    transpose_bf16_kernel<<<dim3(TW / 64, NE / 64), 256, 0, stream>>>(
        w1, (unsigned short*)w1t, NE, TW);     // w1 [NE][TW] -> w1t [TW][NE]
    transpose_bf16_kernel<<<dim3(NE / 64, TW / 64), 256, 0, stream>>>(
        w2, (unsigned short*)w2t, TW, NE);     // w2 [TW][NE] -> w2t [NE][TW]

    // row-tiles of 256: sum_e ceil(cnt_e/256) <= 64 + 7 = 71 -> grid.x = 72
    gemm1_mfma<<<dim3(72, DFFN / TILE_N), 512, 131072, stream>>>(
        xg, w1t, token_list, sel_wt, cnt, off, tile_tab, tile_n, h);
    gemm2_mfma<<<dim3(72, NE / TILE_N, 2), 512, 131072, stream>>>(
        h, w2t, token_list, cnt, off, tile_tab, tile_n, out);
}